// Round 1
// baseline (777.822 us; speedup 1.0000x reference)
//
#include <hip/hip_runtime.h>

typedef unsigned short ushort_t;
typedef __bf16 bf16x8 __attribute__((ext_vector_type(8)));
typedef float f32x4 __attribute__((ext_vector_type(4)));

#define N_NODES 100000
#define D_IN    1024
#define D_OUT   512
#define B_SZ    8192
#define K_NB    64

__device__ __forceinline__ ushort_t f2bf(float f) {
    unsigned int u = __builtin_bit_cast(unsigned int, f);
    u += 0x7FFFu + ((u >> 16) & 1u);   // round-to-nearest-even
    return (ushort_t)(u >> 16);
}

// ---------------------------------------------------------------------------
// Kernel 1: W [D_IN, D_OUT] f32  ->  Wt [D_OUT, D_IN] bf16 (transposed cast)
// Tiny (2 MB source, L2-resident); uncoalesced reads are acceptable.
// ---------------------------------------------------------------------------
__global__ __launch_bounds__(256) void cast_w_kernel(
        const float* __restrict__ W, ushort_t* __restrict__ Wt) {
    int o = blockIdx.x * 256 + threadIdx.x;   // 0 .. D_OUT*D_IN-1
    int n = o >> 10;                          // output row  (0..511)
    int k = o & 1023;                         // output col  (0..1023)
    Wt[o] = f2bf(W[k * D_OUT + n]);
}

// ---------------------------------------------------------------------------
// Kernel 2: Y[b,:] = sum_k val[b,k] * X[idx[b,k],:]   (bf16 out)
//           s[b]   = sum_k val[b,k]
// One block per batch row; 256 threads x float4 = 1024 cols. Rows are 4 KB
// fully-coalesced reads; indices/weights broadcast from LDS.
// ---------------------------------------------------------------------------
__global__ __launch_bounds__(256) void gather_kernel(
        const float* __restrict__ X, const int* __restrict__ idx,
        const float* __restrict__ val, ushort_t* __restrict__ Y,
        float* __restrict__ s) {
    int b = blockIdx.x;
    int t = threadIdx.x;

    __shared__ int   sidx[K_NB];
    __shared__ float sval[K_NB];
    if (t < K_NB) {
        sidx[t] = idx[b * K_NB + t];
        sval[t] = val[b * K_NB + t];
    }
    __syncthreads();

    float ax = 0.f, ay = 0.f, az = 0.f, aw = 0.f;
    #pragma unroll 8
    for (int k = 0; k < K_NB; k++) {
        const float4* row = (const float4*)(X + (size_t)sidx[k] * D_IN);
        float4 x = row[t];
        float  v = sval[k];
        ax = fmaf(v, x.x, ax);
        ay = fmaf(v, x.y, ay);
        az = fmaf(v, x.z, az);
        aw = fmaf(v, x.w, aw);
    }

    uint2 o;
    o.x = (unsigned)f2bf(ax) | ((unsigned)f2bf(ay) << 16);
    o.y = (unsigned)f2bf(az) | ((unsigned)f2bf(aw) << 16);
    *(uint2*)(Y + (size_t)b * D_IN + t * 4) = o;

    if (t == 0) {
        float sum = 0.f;
        #pragma unroll
        for (int k = 0; k < K_NB; k++) sum += sval[k];
        s[b] = sum;
    }
}

// ---------------------------------------------------------------------------
// Kernel 3: out[M,N] = Y[M,K] @ Wt[N,K]^T + s[m]*bias[n]
// M=8192 N=512 K=1024, bf16 MFMA 16x16x32. Block tile 128x128, BK=32,
// 256 threads = 4 waves, each wave owns a 64x64 sub-tile (4x4 MFMA frags).
// A-frag: lane holds A[m = lane&15][k = (lane>>4)*8 + j] (contiguous 16B).
// B-frag: lane holds B[n = lane&15][k = (lane>>4)*8 + j] -> Wt rows contiguous.
// C/D:    col = lane&15, row = (lane>>4)*4 + reg   [verified layout].
// ---------------------------------------------------------------------------
__global__ __launch_bounds__(256) void gemm_kernel(
        const ushort_t* __restrict__ Y, const ushort_t* __restrict__ Wt,
        const float* __restrict__ s, const float* __restrict__ bias,
        float* __restrict__ out) {
    const int Kdim = D_IN;
    int m0 = blockIdx.x * 128;
    int n0 = blockIdx.y * 128;
    int t = threadIdx.x;
    int lane = t & 63;
    int wave = t >> 6;
    int wm = (wave >> 1) * 64;
    int wn = (wave & 1) * 64;
    int quad = lane >> 4;
    int l16  = lane & 15;

    __shared__ __align__(16) ushort_t As[128 * 32];
    __shared__ __align__(16) ushort_t Bs[128 * 32];

    f32x4 acc[4][4];
    f32x4 zero = {0.f, 0.f, 0.f, 0.f};
    #pragma unroll
    for (int i = 0; i < 4; i++)
        #pragma unroll
        for (int j = 0; j < 4; j++)
            acc[i][j] = zero;

    for (int k0 = 0; k0 < Kdim; k0 += 32) {
        // Stage A (128x32) and B (128x32) tiles: 512 16B-chunks each over
        // 256 threads x 2 iterations. Row-major, 64 B per row.
        #pragma unroll
        for (int i = 0; i < 2; i++) {
            int c   = t + i * 256;
            int row = c >> 2;
            int chk = c & 3;
            *(int4*)(As + row * 32 + chk * 8) =
                *(const int4*)(Y + (size_t)(m0 + row) * Kdim + k0 + chk * 8);
            *(int4*)(Bs + row * 32 + chk * 8) =
                *(const int4*)(Wt + (size_t)(n0 + row) * Kdim + k0 + chk * 8);
        }
        __syncthreads();

        bf16x8 a[4], b[4];
        #pragma unroll
        for (int i = 0; i < 4; i++) {
            a[i] = *(const bf16x8*)(As + (wm + i * 16 + l16) * 32 + quad * 8);
            b[i] = *(const bf16x8*)(Bs + (wn + i * 16 + l16) * 32 + quad * 8);
        }
        #pragma unroll
        for (int i = 0; i < 4; i++)
            #pragma unroll
            for (int j = 0; j < 4; j++)
                acc[i][j] = __builtin_amdgcn_mfma_f32_16x16x32_bf16(
                                a[i], b[j], acc[i][j], 0, 0, 0);
        __syncthreads();
    }

    // Epilogue: out = acc + s[row]*bias[col]
    #pragma unroll
    for (int i = 0; i < 4; i++) {
        #pragma unroll
        for (int r = 0; r < 4; r++) {
            int grow = m0 + wm + i * 16 + quad * 4 + r;
            float sv = s[grow];
            #pragma unroll
            for (int j = 0; j < 4; j++) {
                int gcol = n0 + wn + j * 16 + l16;
                out[(size_t)grow * D_OUT + gcol] = acc[i][j][r] + sv * bias[gcol];
            }
        }
    }
}

// ---------------------------------------------------------------------------
extern "C" void kernel_launch(void* const* d_in, const int* in_sizes, int n_in,
                              void* d_out, int out_size, void* d_ws, size_t ws_size,
                              hipStream_t stream) {
    const float* X    = (const float*)d_in[0];
    const int*   idx  = (const int*)d_in[1];
    const float* val  = (const float*)d_in[2];
    const float* W    = (const float*)d_in[3];
    const float* bias = (const float*)d_in[4];
    float* out = (float*)d_out;

    char* ws = (char*)d_ws;
    ushort_t* Yb = (ushort_t*)ws;                                   // 16 MiB
    ushort_t* Wt = (ushort_t*)(ws + (size_t)B_SZ * D_IN * 2);       //  1 MiB
    float*    sb = (float*)(ws + (size_t)B_SZ * D_IN * 2
                               + (size_t)D_OUT * D_IN * 2);         // 32 KiB

    hipLaunchKernelGGL(cast_w_kernel, dim3((D_OUT * D_IN) / 256), dim3(256),
                       0, stream, W, Wt);
    hipLaunchKernelGGL(gather_kernel, dim3(B_SZ), dim3(256),
                       0, stream, X, idx, val, Yb, sb);
    hipLaunchKernelGGL(gemm_kernel, dim3(B_SZ / 128, D_OUT / 128), dim3(256),
                       0, stream, Yb, Wt, sb, bias, out);
}

// Round 2
// 729.864 us; speedup vs baseline: 1.0657x; 1.0657x over previous
//
#include <hip/hip_runtime.h>

typedef unsigned short ushort_t;
typedef __bf16 bf16x8 __attribute__((ext_vector_type(8)));
typedef float f32x4 __attribute__((ext_vector_type(4)));

#define N_NODES 100000
#define D_IN    1024
#define D_OUT   512
#define B_SZ    8192
#define K_NB    64

__device__ __forceinline__ ushort_t f2bf(float f) {
    unsigned int u = __builtin_bit_cast(unsigned int, f);
    u += 0x7FFFu + ((u >> 16) & 1u);   // round-to-nearest-even
    return (ushort_t)(u >> 16);
}
__device__ __forceinline__ float bflo(unsigned d) {
    return __builtin_bit_cast(float, d << 16);
}
__device__ __forceinline__ float bfhi(unsigned d) {
    return __builtin_bit_cast(float, d & 0xFFFF0000u);
}

// ---------------------------------------------------------------------------
// Kernel 1: W [D_IN, D_OUT] f32  ->  Wt [D_OUT, D_IN] bf16 (transposed cast)
// ---------------------------------------------------------------------------
__global__ __launch_bounds__(256) void cast_w_kernel(
        const float* __restrict__ W, ushort_t* __restrict__ Wt) {
    int o = blockIdx.x * 256 + threadIdx.x;
    int n = o >> 10;
    int k = o & 1023;
    Wt[o] = f2bf(W[k * D_OUT + n]);
}

// ---------------------------------------------------------------------------
// Kernel 2: X [N,D_IN] f32 -> Xb [N,D_IN] bf16. Pure streaming.
// 8 elems/thread: 2x float4 in, 1x uint4 (8 bf16) out. 50000 blocks exactly.
// ---------------------------------------------------------------------------
__global__ __launch_bounds__(256) void cast_x_kernel(
        const float* __restrict__ X, ushort_t* __restrict__ Xb) {
    size_t o = ((size_t)blockIdx.x * 256 + threadIdx.x) * 8;
    float4 a = *(const float4*)(X + o);
    float4 b = *(const float4*)(X + o + 4);
    uint4 r;
    r.x = (unsigned)f2bf(a.x) | ((unsigned)f2bf(a.y) << 16);
    r.y = (unsigned)f2bf(a.z) | ((unsigned)f2bf(a.w) << 16);
    r.z = (unsigned)f2bf(b.x) | ((unsigned)f2bf(b.y) << 16);
    r.w = (unsigned)f2bf(b.z) | ((unsigned)f2bf(b.w) << 16);
    *(uint4*)(Xb + o) = r;
}

// ---------------------------------------------------------------------------
// Kernel 3 (fast): Y[b,:] = sum_k val[b,k] * Xb[idx[b,k],:]  (bf16 in+out)
// Rows are 2 KB. 256 threads: half-warp-split over neighbor parity; thread
// (h, c) loads 16 B (8 bf16) at chunk c of neighbor rows k = h, h+2, ...
// Each wave-instr reads 1 KB contiguous from one row. Halves reduce via LDS.
// ---------------------------------------------------------------------------
__global__ __launch_bounds__(256) void gather_bf16_kernel(
        const ushort_t* __restrict__ Xb, const int* __restrict__ idx,
        const float* __restrict__ val, ushort_t* __restrict__ Y,
        float* __restrict__ s) {
    int b = blockIdx.x;
    int t = threadIdx.x;

    __shared__ int   sidx[K_NB];
    __shared__ float sval[K_NB];
    __shared__ float part[128 * 8];
    if (t < K_NB) {
        sidx[t] = idx[b * K_NB + t];
        sval[t] = val[b * K_NB + t];
    }
    __syncthreads();

    int h = t >> 7;      // neighbor parity
    int c = t & 127;     // 16B chunk within the 2KB row

    float acc[8] = {0.f, 0.f, 0.f, 0.f, 0.f, 0.f, 0.f, 0.f};
    #pragma unroll 4
    for (int k = h; k < K_NB; k += 2) {
        const uint4* row = (const uint4*)(Xb + (size_t)sidx[k] * D_IN);
        uint4 x = row[c];
        float v = sval[k];
        acc[0] = fmaf(v, bflo(x.x), acc[0]);
        acc[1] = fmaf(v, bfhi(x.x), acc[1]);
        acc[2] = fmaf(v, bflo(x.y), acc[2]);
        acc[3] = fmaf(v, bfhi(x.y), acc[3]);
        acc[4] = fmaf(v, bflo(x.z), acc[4]);
        acc[5] = fmaf(v, bfhi(x.z), acc[5]);
        acc[6] = fmaf(v, bflo(x.w), acc[6]);
        acc[7] = fmaf(v, bfhi(x.w), acc[7]);
    }

    if (h == 1) {
        #pragma unroll
        for (int e = 0; e < 8; e++) part[c * 8 + e] = acc[e];
    }
    __syncthreads();
    if (h == 0) {
        ushort_t r[8];
        #pragma unroll
        for (int e = 0; e < 8; e++) r[e] = f2bf(acc[e] + part[c * 8 + e]);
        uint4 o;
        o.x = (unsigned)r[0] | ((unsigned)r[1] << 16);
        o.y = (unsigned)r[2] | ((unsigned)r[3] << 16);
        o.z = (unsigned)r[4] | ((unsigned)r[5] << 16);
        o.w = (unsigned)r[6] | ((unsigned)r[7] << 16);
        *(uint4*)(Y + (size_t)b * D_IN + c * 8) = o;
    }
    if (t == 0) {
        float sum = 0.f;
        #pragma unroll
        for (int k = 0; k < K_NB; k++) sum += sval[k];
        s[b] = sum;
    }
}

// ---------------------------------------------------------------------------
// Kernel 3 (fallback, fp32 X): previous round's gather. Used if ws too small.
// ---------------------------------------------------------------------------
__global__ __launch_bounds__(256) void gather_f32_kernel(
        const float* __restrict__ X, const int* __restrict__ idx,
        const float* __restrict__ val, ushort_t* __restrict__ Y,
        float* __restrict__ s) {
    int b = blockIdx.x;
    int t = threadIdx.x;

    __shared__ int   sidx[K_NB];
    __shared__ float sval[K_NB];
    if (t < K_NB) {
        sidx[t] = idx[b * K_NB + t];
        sval[t] = val[b * K_NB + t];
    }
    __syncthreads();

    float ax = 0.f, ay = 0.f, az = 0.f, aw = 0.f;
    #pragma unroll 8
    for (int k = 0; k < K_NB; k++) {
        const float4* row = (const float4*)(X + (size_t)sidx[k] * D_IN);
        float4 x = row[t];
        float  v = sval[k];
        ax = fmaf(v, x.x, ax);
        ay = fmaf(v, x.y, ay);
        az = fmaf(v, x.z, az);
        aw = fmaf(v, x.w, aw);
    }
    uint2 o;
    o.x = (unsigned)f2bf(ax) | ((unsigned)f2bf(ay) << 16);
    o.y = (unsigned)f2bf(az) | ((unsigned)f2bf(aw) << 16);
    *(uint2*)(Y + (size_t)b * D_IN + t * 4) = o;

    if (t == 0) {
        float sum = 0.f;
        #pragma unroll
        for (int k = 0; k < K_NB; k++) sum += sval[k];
        s[b] = sum;
    }
}

// ---------------------------------------------------------------------------
// Kernel 4: out[M,N] = Y[M,K] @ Wt[N,K]^T + s[m]*bias[n]
// M=8192 N=512 K=1024, bf16 MFMA 16x16x32, 128x128 block tile, BK=32.
// LDS chunk placement XOR-swizzled by row bits 2:3 so both the staging
// writes and the fragment ds_read_b128s are 2-way (free) instead of 8-way.
// ---------------------------------------------------------------------------
__global__ __launch_bounds__(256) void gemm_kernel(
        const ushort_t* __restrict__ Y, const ushort_t* __restrict__ Wt,
        const float* __restrict__ s, const float* __restrict__ bias,
        float* __restrict__ out) {
    const int Kdim = D_IN;
    int m0 = blockIdx.x * 128;
    int n0 = blockIdx.y * 128;
    int t = threadIdx.x;
    int lane = t & 63;
    int wave = t >> 6;
    int wm = (wave >> 1) * 64;
    int wn = (wave & 1) * 64;
    int quad = lane >> 4;
    int l16  = lane & 15;

    __shared__ __align__(16) ushort_t As[128 * 32];
    __shared__ __align__(16) ushort_t Bs[128 * 32];

    f32x4 acc[4][4];
    f32x4 zero = {0.f, 0.f, 0.f, 0.f};
    #pragma unroll
    for (int i = 0; i < 4; i++)
        #pragma unroll
        for (int j = 0; j < 4; j++)
            acc[i][j] = zero;

    int rsw = (l16 >> 2) & 3;   // read-side swizzle key (row bits 2:3)

    for (int k0 = 0; k0 < Kdim; k0 += 32) {
        #pragma unroll
        for (int i = 0; i < 2; i++) {
            int c   = t + i * 256;
            int row = c >> 2;
            int chk = c & 3;
            int pos = chk ^ ((row >> 2) & 3);   // XOR swizzle
            *(int4*)(As + row * 32 + pos * 8) =
                *(const int4*)(Y + (size_t)(m0 + row) * Kdim + k0 + chk * 8);
            *(int4*)(Bs + row * 32 + pos * 8) =
                *(const int4*)(Wt + (size_t)(n0 + row) * Kdim + k0 + chk * 8);
        }
        __syncthreads();

        bf16x8 a[4], b[4];
        int rchk = quad ^ rsw;
        #pragma unroll
        for (int i = 0; i < 4; i++) {
            a[i] = *(const bf16x8*)(As + (wm + i * 16 + l16) * 32 + rchk * 8);
            b[i] = *(const bf16x8*)(Bs + (wn + i * 16 + l16) * 32 + rchk * 8);
        }
        #pragma unroll
        for (int i = 0; i < 4; i++)
            #pragma unroll
            for (int j = 0; j < 4; j++)
                acc[i][j] = __builtin_amdgcn_mfma_f32_16x16x32_bf16(
                                a[i], b[j], acc[i][j], 0, 0, 0);
        __syncthreads();
    }

    #pragma unroll
    for (int i = 0; i < 4; i++) {
        #pragma unroll
        for (int r = 0; r < 4; r++) {
            int grow = m0 + wm + i * 16 + quad * 4 + r;
            float sv = s[grow];
            #pragma unroll
            for (int j = 0; j < 4; j++) {
                int gcol = n0 + wn + j * 16 + l16;
                out[(size_t)grow * D_OUT + gcol] = acc[i][j][r] + sv * bias[gcol];
            }
        }
    }
}

// ---------------------------------------------------------------------------
extern "C" void kernel_launch(void* const* d_in, const int* in_sizes, int n_in,
                              void* d_out, int out_size, void* d_ws, size_t ws_size,
                              hipStream_t stream) {
    const float* X    = (const float*)d_in[0];
    const int*   idx  = (const int*)d_in[1];
    const float* val  = (const float*)d_in[2];
    const float* W    = (const float*)d_in[3];
    const float* bias = (const float*)d_in[4];
    float* out = (float*)d_out;

    const size_t XB_BYTES = (size_t)N_NODES * D_IN * 2;   // 204,800,000
    const size_t Y_BYTES  = (size_t)B_SZ * D_IN * 2;      //  16,777,216
    const size_t WT_BYTES = (size_t)D_OUT * D_IN * 2;     //   1,048,576
    const size_t S_BYTES  = (size_t)B_SZ * 4;             //      32,768

    char* ws = (char*)d_ws;
    bool fast = ws_size >= XB_BYTES + Y_BYTES + WT_BYTES + S_BYTES;

    ushort_t *Xb, *Yb, *Wt;
    float *sb;
    if (fast) {
        Xb = (ushort_t*)ws;
        Yb = (ushort_t*)(ws + XB_BYTES);
        Wt = (ushort_t*)(ws + XB_BYTES + Y_BYTES);
        sb = (float*)(ws + XB_BYTES + Y_BYTES + WT_BYTES);
    } else {
        Xb = nullptr;
        Yb = (ushort_t*)ws;
        Wt = (ushort_t*)(ws + Y_BYTES);
        sb = (float*)(ws + Y_BYTES + WT_BYTES);
    }

    hipLaunchKernelGGL(cast_w_kernel, dim3((D_OUT * D_IN) / 256), dim3(256),
                       0, stream, W, Wt);
    if (fast) {
        hipLaunchKernelGGL(cast_x_kernel, dim3((N_NODES * D_IN) / (256 * 8)),
                           dim3(256), 0, stream, X, Xb);
        hipLaunchKernelGGL(gather_bf16_kernel, dim3(B_SZ), dim3(256),
                           0, stream, Xb, idx, val, Yb, sb);
    } else {
        hipLaunchKernelGGL(gather_f32_kernel, dim3(B_SZ), dim3(256),
                           0, stream, X, idx, val, Yb, sb);
    }
    hipLaunchKernelGGL(gemm_kernel, dim3(B_SZ / 128, D_OUT / 128), dim3(256),
                       0, stream, Yb, Wt, sb, bias, out);
}

// Round 3
// 729.431 us; speedup vs baseline: 1.0663x; 1.0006x over previous
//
#include <hip/hip_runtime.h>

typedef unsigned short ushort_t;
typedef __bf16 bf16x8 __attribute__((ext_vector_type(8)));
typedef float f32x4 __attribute__((ext_vector_type(4)));

#define N_NODES 100000
#define D_IN    1024
#define D_OUT   512
#define B_SZ    8192
#define K_NB    64

__device__ __forceinline__ ushort_t f2bf(float f) {
    unsigned int u = __builtin_bit_cast(unsigned int, f);
    u += 0x7FFFu + ((u >> 16) & 1u);   // round-to-nearest-even
    return (ushort_t)(u >> 16);
}
__device__ __forceinline__ float bflo(unsigned d) {
    return __builtin_bit_cast(float, d << 16);
}
__device__ __forceinline__ float bfhi(unsigned d) {
    return __builtin_bit_cast(float, d & 0xFFFF0000u);
}

// ---------------------------------------------------------------------------
// Kernel 1: W [D_IN, D_OUT] f32  ->  Wt [D_OUT, D_IN] bf16 (transposed cast)
// ---------------------------------------------------------------------------
__global__ __launch_bounds__(256) void cast_w_kernel(
        const float* __restrict__ W, ushort_t* __restrict__ Wt) {
    int o = blockIdx.x * 256 + threadIdx.x;
    int n = o >> 10;
    int k = o & 1023;
    Wt[o] = f2bf(W[k * D_OUT + n]);
}

// ---------------------------------------------------------------------------
// Kernel 2: X [N,D_IN] f32 -> Xb [N,D_IN] bf16. Pure streaming (615 MB, at
// the HBM floor ~98 us; do not touch).
// ---------------------------------------------------------------------------
__global__ __launch_bounds__(256) void cast_x_kernel(
        const float* __restrict__ X, ushort_t* __restrict__ Xb) {
    size_t o = ((size_t)blockIdx.x * 256 + threadIdx.x) * 8;
    float4 a = *(const float4*)(X + o);
    float4 b = *(const float4*)(X + o + 4);
    uint4 r;
    r.x = (unsigned)f2bf(a.x) | ((unsigned)f2bf(a.y) << 16);
    r.y = (unsigned)f2bf(a.z) | ((unsigned)f2bf(a.w) << 16);
    r.z = (unsigned)f2bf(b.x) | ((unsigned)f2bf(b.y) << 16);
    r.w = (unsigned)f2bf(b.z) | ((unsigned)f2bf(b.w) << 16);
    *(uint4*)(Xb + o) = r;
}

// ---------------------------------------------------------------------------
// Kernel 3 (fast): Y[b,:] = sum_k val[b,k] * Xb[idx[b,k],:]  (bf16 in+out)
// Software-pipelined: 8 uint4 loads in flight per thread (prefetch next
// group while FMA-ing current group) -> ~4x the MLP of the unroll-4 version.
// Thread (h = t>>7, c = t&127): 16B chunk c of neighbor rows k = h, h+2, ...
// ---------------------------------------------------------------------------
__global__ __launch_bounds__(256) void gather_bf16_kernel(
        const ushort_t* __restrict__ Xb, const int* __restrict__ idx,
        const float* __restrict__ val, ushort_t* __restrict__ Y,
        float* __restrict__ s) {
    int b = blockIdx.x;
    int t = threadIdx.x;

    __shared__ int   sidx[K_NB];
    __shared__ float sval[K_NB];
    __shared__ float part[128 * 8];
    if (t < K_NB) {
        sidx[t] = idx[b * K_NB + t];
        sval[t] = val[b * K_NB + t];
    }
    __syncthreads();

    int h = t >> 7;      // neighbor parity: rows k = h + 2*j, j = 0..31
    int c = t & 127;     // 16B chunk within the 2KB row

    float acc[8] = {0.f, 0.f, 0.f, 0.f, 0.f, 0.f, 0.f, 0.f};

    uint4 x[8];
    #pragma unroll
    for (int u = 0; u < 8; u++)
        x[u] = ((const uint4*)(Xb + (size_t)sidx[h + 2 * u] * D_IN))[c];

    #pragma unroll
    for (int j0 = 0; j0 < 32; j0 += 8) {
        uint4 cur[8];
        #pragma unroll
        for (int u = 0; u < 8; u++) cur[u] = x[u];
        if (j0 + 8 < 32) {
            #pragma unroll
            for (int u = 0; u < 8; u++)
                x[u] = ((const uint4*)(
                    Xb + (size_t)sidx[h + 2 * (j0 + 8 + u)] * D_IN))[c];
        }
        #pragma unroll
        for (int u = 0; u < 8; u++) {
            float v = sval[h + 2 * (j0 + u)];
            acc[0] = fmaf(v, bflo(cur[u].x), acc[0]);
            acc[1] = fmaf(v, bfhi(cur[u].x), acc[1]);
            acc[2] = fmaf(v, bflo(cur[u].y), acc[2]);
            acc[3] = fmaf(v, bfhi(cur[u].y), acc[3]);
            acc[4] = fmaf(v, bflo(cur[u].z), acc[4]);
            acc[5] = fmaf(v, bfhi(cur[u].z), acc[5]);
            acc[6] = fmaf(v, bflo(cur[u].w), acc[6]);
            acc[7] = fmaf(v, bfhi(cur[u].w), acc[7]);
        }
    }

    if (h == 1) {
        #pragma unroll
        for (int e = 0; e < 8; e++) part[c * 8 + e] = acc[e];
    }
    __syncthreads();
    if (h == 0) {
        ushort_t r[8];
        #pragma unroll
        for (int e = 0; e < 8; e++) r[e] = f2bf(acc[e] + part[c * 8 + e]);
        uint4 o;
        o.x = (unsigned)r[0] | ((unsigned)r[1] << 16);
        o.y = (unsigned)r[2] | ((unsigned)r[3] << 16);
        o.z = (unsigned)r[4] | ((unsigned)r[5] << 16);
        o.w = (unsigned)r[6] | ((unsigned)r[7] << 16);
        *(uint4*)(Y + (size_t)b * D_IN + c * 8) = o;
    }
    if (t == 0) {
        float sum = 0.f;
        #pragma unroll
        for (int k = 0; k < K_NB; k++) sum += sval[k];
        s[b] = sum;
    }
}

// ---------------------------------------------------------------------------
// Kernel 3 (fallback, fp32 X): used only if ws too small for Xb.
// ---------------------------------------------------------------------------
__global__ __launch_bounds__(256) void gather_f32_kernel(
        const float* __restrict__ X, const int* __restrict__ idx,
        const float* __restrict__ val, ushort_t* __restrict__ Y,
        float* __restrict__ s) {
    int b = blockIdx.x;
    int t = threadIdx.x;

    __shared__ int   sidx[K_NB];
    __shared__ float sval[K_NB];
    if (t < K_NB) {
        sidx[t] = idx[b * K_NB + t];
        sval[t] = val[b * K_NB + t];
    }
    __syncthreads();

    float ax = 0.f, ay = 0.f, az = 0.f, aw = 0.f;
    #pragma unroll 8
    for (int k = 0; k < K_NB; k++) {
        const float4* row = (const float4*)(X + (size_t)sidx[k] * D_IN);
        float4 x = row[t];
        float  v = sval[k];
        ax = fmaf(v, x.x, ax);
        ay = fmaf(v, x.y, ay);
        az = fmaf(v, x.z, az);
        aw = fmaf(v, x.w, aw);
    }
    uint2 o;
    o.x = (unsigned)f2bf(ax) | ((unsigned)f2bf(ay) << 16);
    o.y = (unsigned)f2bf(az) | ((unsigned)f2bf(aw) << 16);
    *(uint2*)(Y + (size_t)b * D_IN + t * 4) = o;

    if (t == 0) {
        float sum = 0.f;
        #pragma unroll
        for (int k = 0; k < K_NB; k++) sum += sval[k];
        s[b] = sum;
    }
}

// ---------------------------------------------------------------------------
// Kernel 4: out[M,N] = Y[M,K] @ Wt[N,K]^T + s[m]*bias[n]
// bf16 MFMA 16x16x32, 128x128 tile, BK=32, XOR-swizzled LDS (2-way = free).
// Unchanged from R2 (passed, ~25 us, not the bottleneck).
// ---------------------------------------------------------------------------
__global__ __launch_bounds__(256) void gemm_kernel(
        const ushort_t* __restrict__ Y, const ushort_t* __restrict__ Wt,
        const float* __restrict__ s, const float* __restrict__ bias,
        float* __restrict__ out) {
    const int Kdim = D_IN;
    int m0 = blockIdx.x * 128;
    int n0 = blockIdx.y * 128;
    int t = threadIdx.x;
    int lane = t & 63;
    int wave = t >> 6;
    int wm = (wave >> 1) * 64;
    int wn = (wave & 1) * 64;
    int quad = lane >> 4;
    int l16  = lane & 15;

    __shared__ __align__(16) ushort_t As[128 * 32];
    __shared__ __align__(16) ushort_t Bs[128 * 32];

    f32x4 acc[4][4];
    f32x4 zero = {0.f, 0.f, 0.f, 0.f};
    #pragma unroll
    for (int i = 0; i < 4; i++)
        #pragma unroll
        for (int j = 0; j < 4; j++)
            acc[i][j] = zero;

    int rsw = (l16 >> 2) & 3;

    for (int k0 = 0; k0 < Kdim; k0 += 32) {
        #pragma unroll
        for (int i = 0; i < 2; i++) {
            int c   = t + i * 256;
            int row = c >> 2;
            int chk = c & 3;
            int pos = chk ^ ((row >> 2) & 3);
            *(int4*)(As + row * 32 + pos * 8) =
                *(const int4*)(Y + (size_t)(m0 + row) * Kdim + k0 + chk * 8);
            *(int4*)(Bs + row * 32 + pos * 8) =
                *(const int4*)(Wt + (size_t)(n0 + row) * Kdim + k0 + chk * 8);
        }
        __syncthreads();

        bf16x8 a[4], b[4];
        int rchk = quad ^ rsw;
        #pragma unroll
        for (int i = 0; i < 4; i++) {
            a[i] = *(const bf16x8*)(As + (wm + i * 16 + l16) * 32 + rchk * 8);
            b[i] = *(const bf16x8*)(Bs + (wn + i * 16 + l16) * 32 + rchk * 8);
        }
        #pragma unroll
        for (int i = 0; i < 4; i++)
            #pragma unroll
            for (int j = 0; j < 4; j++)
                acc[i][j] = __builtin_amdgcn_mfma_f32_16x16x32_bf16(
                                a[i], b[j], acc[i][j], 0, 0, 0);
        __syncthreads();
    }

    #pragma unroll
    for (int i = 0; i < 4; i++) {
        #pragma unroll
        for (int r = 0; r < 4; r++) {
            int grow = m0 + wm + i * 16 + quad * 4 + r;
            float sv = s[grow];
            #pragma unroll
            for (int j = 0; j < 4; j++) {
                int gcol = n0 + wn + j * 16 + l16;
                out[(size_t)grow * D_OUT + gcol] = acc[i][j][r] + sv * bias[gcol];
            }
        }
    }
}

// ---------------------------------------------------------------------------
extern "C" void kernel_launch(void* const* d_in, const int* in_sizes, int n_in,
                              void* d_out, int out_size, void* d_ws, size_t ws_size,
                              hipStream_t stream) {
    const float* X    = (const float*)d_in[0];
    const int*   idx  = (const int*)d_in[1];
    const float* val  = (const float*)d_in[2];
    const float* W    = (const float*)d_in[3];
    const float* bias = (const float*)d_in[4];
    float* out = (float*)d_out;

    const size_t XB_BYTES = (size_t)N_NODES * D_IN * 2;
    const size_t Y_BYTES  = (size_t)B_SZ * D_IN * 2;
    const size_t WT_BYTES = (size_t)D_OUT * D_IN * 2;
    const size_t S_BYTES  = (size_t)B_SZ * 4;

    char* ws = (char*)d_ws;
    bool fast = ws_size >= XB_BYTES + Y_BYTES + WT_BYTES + S_BYTES;

    ushort_t *Xb, *Yb, *Wt;
    float *sb;
    if (fast) {
        Xb = (ushort_t*)ws;
        Yb = (ushort_t*)(ws + XB_BYTES);
        Wt = (ushort_t*)(ws + XB_BYTES + Y_BYTES);
        sb = (float*)(ws + XB_BYTES + Y_BYTES + WT_BYTES);
    } else {
        Xb = nullptr;
        Yb = (ushort_t*)ws;
        Wt = (ushort_t*)(ws + Y_BYTES);
        sb = (float*)(ws + Y_BYTES + WT_BYTES);
    }

    hipLaunchKernelGGL(cast_w_kernel, dim3((D_OUT * D_IN) / 256), dim3(256),
                       0, stream, W, Wt);
    if (fast) {
        hipLaunchKernelGGL(cast_x_kernel, dim3((N_NODES * D_IN) / (256 * 8)),
                           dim3(256), 0, stream, X, Xb);
        hipLaunchKernelGGL(gather_bf16_kernel, dim3(B_SZ), dim3(256),
                           0, stream, Xb, idx, val, Yb, sb);
    } else {
        hipLaunchKernelGGL(gather_f32_kernel, dim3(B_SZ), dim3(256),
                           0, stream, X, idx, val, Yb, sb);
    }
    hipLaunchKernelGGL(gemm_kernel, dim3(B_SZ / 128, D_OUT / 128), dim3(256),
                       0, stream, Yb, Wt, sb, bias, out);
}